// Round 1
// 347.093 us; speedup vs baseline: 2.0885x; 2.0885x over previous
//
#include <hip/hip_runtime.h>
#include <stdint.h>

static constexpr int HIN = 256, WIN = 256, HO = 254, WOUT = 254, NB = 8;
static constexpr int PLANE = HO * WOUT;       // 64516
static constexpr int PIX = NB * PLANE;        // 516128

// Ring connectivity: prev atom j feeds next atoms (2j..2j+3) mod a_next.
// Morton-spread mask (j -> bit 2j), duplicate to (2j,2j+1), OR rotate-left-2.
__device__ __forceinline__ uint64_t spread_pairs(uint64_t mask, int a_next) {
  uint64_t s = mask;
  s = (s | (s << 16)) & 0x0000FFFF0000FFFFull;
  s = (s | (s << 8))  & 0x00FF00FF00FF00FFull;
  s = (s | (s << 4))  & 0x0F0F0F0F0F0F0F0Full;
  s = (s | (s << 2))  & 0x3333333333333333ull;
  s = (s | (s << 1))  & 0x5555555555555555ull;
  uint64_t pair = s | (s << 1);
  uint64_t lim = (a_next >= 64) ? ~0ull : ((1ull << a_next) - 1ull);
  uint64_t rot = ((pair << 2) | (pair >> (a_next - 2))) & lim;
  return (pair | rot) & lim;
}

// Bitonic sort (descending) of K uint32 in registers. K power of 2, fully
// unrolled => all indices static => stays in VGPRs. Pure v_min_u32/v_max_u32,
// no VCC/SALU chains, log^2-depth parallelism.
template<int K>
__device__ __forceinline__ void bsort_desc(uint32_t (&v)[K]) {
#pragma unroll
  for (int sz = 2; sz <= K; sz <<= 1) {
#pragma unroll
    for (int st = sz >> 1; st > 0; st >>= 1) {
#pragma unroll
      for (int i = 0; i < K; ++i) {
        int l = i ^ st;
        if (l > i) {
          uint32_t a = v[i], c = v[l];
          uint32_t mx = a > c ? a : c;
          uint32_t mn = a > c ? c : a;
          bool desc = ((i & sz) == 0);
          v[i] = desc ? mx : mn;
          v[l] = desc ? mn : mx;
        }
      }
    }
  }
}

// Bitonic cleanup merge (descending) of an already-bitonic K-sequence.
template<int K>
__device__ __forceinline__ void bmerge_desc(uint32_t (&v)[K]) {
#pragma unroll
  for (int st = K >> 1; st > 0; st >>= 1) {
#pragma unroll
    for (int i = 0; i < K; ++i) {
      int l = i ^ st;
      if (l > i) {
        uint32_t a = v[i], c = v[l];
        v[i] = a > c ? a : c;
        v[l] = a > c ? c : a;
      }
    }
  }
}

// One level. Conv numerics (validated round 7): single f32 accumulator from 0,
// sequential __fmaf_rn over the patch in (ky, kx, c) order — channels
// innermost (NHWC/HWIO im2col+sgemm mirror) — bias added last, separate add.
// Selection: jax top_k semantics — exactly K kept, ties at the boundary
// broken toward LOWEST channel index.
//
// Threshold m (K-th largest |act| WITH multiplicity) is found via a grouped
// bitonic top-K network on the uint32 bit patterns of |act| (bit order ==
// value order for non-negative floats): sort N/K groups of K descending,
// merge pairwise keeping top-K; m = min of the final top-K multiset.
// Identical m to the old K-pass scan; the exact base/quota tie-break keep
// loop below is unchanged.
template<int N, int K, bool GATE>
__device__ __forceinline__ uint64_t do_level(const float (&px)[27],
    const float* __restrict__ w, const float* __restrict__ b,
    int ch0, uint64_t allow, float* __restrict__ out, size_t out_base) {
  float act[N];
#pragma unroll
  for (int j = 0; j < N; ++j) {
    const float* wp = w + (size_t)(ch0 + j) * 27;   // layout (c,ky,kx) per atom
    float acc = 0.0f;
#pragma unroll
    for (int ky = 0; ky < 3; ++ky)
#pragma unroll
      for (int kx = 0; kx < 3; ++kx)
#pragma unroll
        for (int c = 0; c < 3; ++c) {
          int t = c * 9 + ky * 3 + kx;              // source layout index
          acc = __fmaf_rn(px[t], wp[t], acc);       // (ky,kx,c)-ordered FMA chain
        }
    acc = __fadd_rn(acc, b[ch0 + j]);               // bias after conv
    if (GATE) acc = ((allow >> j) & 1ull) ? acc : 0.0f;
    act[j] = acc;
  }

  // ---- threshold via grouped bitonic top-K (G = N/K = 4 for all levels) ----
  constexpr int G = N / K;
  uint32_t run[K];
#pragma unroll
  for (int i = 0; i < K; ++i)
    run[i] = __float_as_uint(act[i]) & 0x7fffffffu;
  bsort_desc<K>(run);

  uint32_t mb = 0;
#pragma unroll
  for (int g = 1; g < G; ++g) {
    uint32_t tmp[K];
#pragma unroll
    for (int i = 0; i < K; ++i)
      tmp[i] = __float_as_uint(act[g * K + i]) & 0x7fffffffu;
    bsort_desc<K>(tmp);
    // top-K of (run desc, tmp desc): elementwise max against reversed tmp
#pragma unroll
    for (int i = 0; i < K; ++i) {
      uint32_t c = tmp[K - 1 - i];
      run[i] = run[i] > c ? run[i] : c;
    }
    if (g < G - 1) {
      bmerge_desc<K>(run);          // re-sort for the next merge
    } else {
      mb = run[0];                  // last merge: only need min of top-K
#pragma unroll
      for (int i = 1; i < K; ++i) mb = mb < run[i] ? mb : run[i];
    }
  }
  float m = __uint_as_float(mb);    // K-th largest |act| with multiplicity

  // base = #{ |a| > m }; quota = boundary-tied survivors, lowest index first.
  int base = 0;
#pragma unroll
  for (int j = 0; j < N; ++j) base += (fabsf(act[j]) > m) ? 1 : 0;
  int quota = K - base;

  uint64_t msk = 0;
#pragma unroll
  for (int j = 0; j < N; ++j) {
    float aj = fabsf(act[j]);
    bool eq = (aj == m);
    bool keep = (aj > m) || (eq && quota > 0);
    quota -= eq ? 1 : 0;
    float v = keep ? act[j] : 0.0f;
    out[out_base + (size_t)(ch0 + j) * PLANE] = v;
    msk |= (v != 0.0f) ? (1ull << j) : 0ull;
  }
  return msk;
}

// __launch_bounds__(256, 4): 4 waves/SIMD => 128-VGPR cap. Peak live set is
// ~105 (act[64] + run[16] + tmp[16] + misc; px[27] dead before selection),
// so this eliminates the scratch spills the old 76-VGPR allocation forced.
__global__ __launch_bounds__(256, 4)
void hrtk_main(const float* __restrict__ x, const float* __restrict__ w,
               const float* __restrict__ b, float* __restrict__ out) {
  int p = blockIdx.x * blockDim.x + threadIdx.x;
  if (p >= PIX) return;
  int bi = p / PLANE;
  int r  = p % PLANE;
  int h  = r / WOUT;
  int wc = r % WOUT;

  float px[27];
  const float* xb = x + (size_t)bi * 3 * HIN * WIN;
#pragma unroll
  for (int c = 0; c < 3; ++c)
#pragma unroll
    for (int dy = 0; dy < 3; ++dy)
#pragma unroll
      for (int dx = 0; dx < 3; ++dx)
        px[c * 9 + dy * 3 + dx] =
            xb[c * HIN * WIN + (size_t)(h + dy) * WIN + (wc + dx)];

  size_t out_base = (size_t)bi * 120 * PLANE + (size_t)h * WOUT + wc;

  uint64_t m0 = do_level<8, 2, false>(px, w, b, 0, 0, out, out_base);
  uint64_t a1 = spread_pairs(m0, 16);
  uint64_t m1 = do_level<16, 4, true>(px, w, b, 8, a1, out, out_base);
  uint64_t a2 = spread_pairs(m1, 32);
  uint64_t m2 = do_level<32, 8, true>(px, w, b, 24, a2, out, out_base);
  uint64_t a3 = spread_pairs(m2, 64);
  (void)do_level<64, 16, true>(px, w, b, 56, a3, out, out_base);
}

extern "C" void kernel_launch(void* const* d_in, const int* in_sizes, int n_in,
                              void* d_out, int out_size, void* d_ws, size_t ws_size,
                              hipStream_t stream) {
  const float* x = (const float*)d_in[0];
  const float* w = (const float*)d_in[1];
  const float* b = (const float*)d_in[2];
  float* out = (float*)d_out;
  dim3 blk(256), grid((PIX + 255) / 256);
  hrtk_main<<<grid, blk, 0, stream>>>(x, w, b, out);
}